// Round 6
// baseline (365.706 us; speedup 1.0000x reference)
//
#include <hip/hip_runtime.h>
#include <hip/hip_bf16.h>

#define NB 262144   // batch
#define KD 512      // in_dim
#define ED 10000    // embed_dim

typedef __attribute__((ext_vector_type(8))) short s8v;
typedef __attribute__((ext_vector_type(4))) float f4v;

typedef __attribute__((address_space(1))) const unsigned int gu32_t;
typedef __attribute__((address_space(3))) unsigned int lu32_t;

__device__ __forceinline__ short f2bf(float f) {
  union { __hip_bfloat16 h; short s; } u;
  u.h = __float2bfloat16(f);
  return u.s;
}

// ---------------- prep (merged): W pack + embT transpose ----------------
__global__ void prep_all(const float* __restrict__ Wlv, const float* __restrict__ Wmu,
                         unsigned short* __restrict__ wbf,
                         const float* __restrict__ We, const float* __restrict__ be,
                         float* __restrict__ embT) {
  __shared__ float t[32][129];
  if (blockIdx.x < 512) {
    int i = blockIdx.x * 256 + threadIdx.x;          // [0, 131072)
    int row = i >> 9, col = i & 511;
    float v = (row < 128) ? Wlv[(row << 9) | col] : Wmu[((row - 128) << 9) | col];
    union { __hip_bfloat16 h; unsigned short s; } u;
    u.h = __float2bfloat16(v);
    wbf[i] = u.s;
  } else {
    const int v0 = (blockIdx.x - 512) << 5;
#pragma unroll
    for (int j = 0; j < 16; ++j) {
      int idx = j * 256 + threadIdx.x;               // [0, 4096)
      int l = idx >> 5, vi = idx & 31;
      int v = v0 + vi;
      t[vi][l] = (v < ED) ? We[(size_t)l * ED + v] : 0.f;
    }
    __syncthreads();
#pragma unroll
    for (int j = 0; j < 16; ++j) {
      int idx = j * 256 + threadIdx.x;
      int v = idx >> 7, l = idx & 127;
      if (v0 + v < ED)
        embT[(size_t)(v0 + v) * 128 + l] = t[v][l] + be[l];
    }
  }
}

// ---------------- main GEMM: one-shot contiguous x-stage, barrier-free loop ----------------
// Per block: stage x[gm..gm+32][0..512] fp32 (64KB, CONTIGUOUS range of x) into LDS,
// ONE vmcnt(0)+barrier, then 16 K-tiles of {B reg-loads from L2-hot wbf, A ds_read,
// 4 MFMA} with no barriers. 8 waves, each 32 rows x 32 cols (wn=wid). 2 blocks/CU.
__global__ __launch_bounds__(512, 4) void gemm_heads(
    const float* __restrict__ x, const unsigned short* __restrict__ wbf,
    const float* __restrict__ blv, const float* __restrict__ bmu,
    const int* __restrict__ y, const float* __restrict__ embT,
    float* __restrict__ out, int doEmbed) {
  __shared__ char lds[65536];
  const int tid  = threadIdx.x;
  const int lane = tid & 63;
  const int wid  = tid >> 6;   // 0..7 = column group (32 cols each)
  const int gm   = blockIdx.x << 5;
  const int lr   = lane & 15;
  const int kg   = lane >> 4;

  // ---- stage: chunk c (16B): row=c>>7, q=c&127; LDS dst byte = c*16 (linear);
  // stored chunk is source chunk (row, q ^ (row&7)) -> swizzle lives in the source
  // address but only permutes within 128B sub-blocks: wave footprint stays a
  // contiguous 1KB of x, rows of the tile form one contiguous 64KB range.
  const float* xblk = x + ((size_t)gm << 9);
#pragma unroll
  for (int j = 0; j < 8; ++j) {
    int c = (j << 9) + tid;
    int row = c >> 7, q = c & 127;
    unsigned src = (unsigned)(row << 9) + (unsigned)((q ^ (row & 7)) << 2);
    __builtin_amdgcn_global_load_lds((const gu32_t*)(xblk + src),
                                     (lu32_t*)(lds + (c << 4)), 16, 0, 0);
  }
  asm volatile("s_waitcnt vmcnt(0)" ::: "memory");
  __builtin_amdgcn_s_barrier();

  // ---- B pointers: wave's 32 cols (2 groups of 16), 16B per lane per tile
  const unsigned short* pb0 = wbf + (((size_t)((wid << 5) + lr)) << 9) + (kg << 3);
  const unsigned short* pb1 = pb0 + (16 << 9);

  f4v acc[2][2];
#pragma unroll
  for (int m = 0; m < 2; ++m)
#pragma unroll
    for (int n = 0; n < 2; ++n) acc[m][n] = (f4v)0.f;

#pragma unroll
  for (int kt = 0; kt < 16; ++kt) {
    s8v bfr[2];
    bfr[0] = *(const s8v*)(pb0 + (kt << 5));
    bfr[1] = *(const s8v*)(pb1 + (kt << 5));
    s8v af[2];
#pragma unroll
    for (int m = 0; m < 2; ++m) {
      int row = (m << 4) + lr;
      int ch = (kt << 3) + (kg << 1);
      int sw = row & 7;
      float4 a0 = *(const float4*)(lds + (row << 11) + (((ch)     ^ sw) << 4));
      float4 a1 = *(const float4*)(lds + (row << 11) + (((ch + 1) ^ sw) << 4));
      af[m][0] = f2bf(a0.x); af[m][1] = f2bf(a0.y); af[m][2] = f2bf(a0.z); af[m][3] = f2bf(a0.w);
      af[m][4] = f2bf(a1.x); af[m][5] = f2bf(a1.y); af[m][6] = f2bf(a1.z); af[m][7] = f2bf(a1.w);
    }
#pragma unroll
    for (int m = 0; m < 2; ++m)
#pragma unroll
      for (int n = 0; n < 2; ++n)
        acc[m][n] = __builtin_amdgcn_mfma_f32_16x16x32_bf16(af[m], bfr[n], acc[m][n], 0, 0, 0);
  }

  // ---- epilogue: C/D layout col=lane&15, row=(lane>>4)*4+r (validated r1/r4/r5)
  const int rsub = kg << 2;
#pragma unroll
  for (int n = 0; n < 2; ++n) {
    int col = (wid << 5) + (n << 4) + lr;
    float bias = (col < 128) ? blv[col] : bmu[col - 128];
    float* ob = (col < 128) ? (out + col)
                            : (out + ((size_t)NB << 7) + (col - 128));
#pragma unroll
    for (int m = 0; m < 2; ++m) {
      int row0 = gm + (m << 4) + rsub;
#pragma unroll
      for (int r = 0; r < 4; ++r)
        ob[(size_t)(row0 + r) << 7] = acc[m][n][r] + bias;
    }
  }

  // ---- fused embed: this block's 32 rows; embT is L2-resident
  if (doEmbed) {
    float* out3 = out + ((size_t)NB << 8);
    int r  = tid >> 4;            // 0..31
    int c0 = (tid & 15) << 3;     // 0..120 floats (32B per thread)
    int row = gm + r;
    int v = y[row];
    const float4* src = (const float4*)(embT + (size_t)v * 128 + c0);
    float4* dst = (float4*)(out3 + ((size_t)row << 7) + c0);
    dst[0] = src[0];
    dst[1] = src[1];
  }
}

// ---------------- fallbacks (only if ws_size too small) ----------------
__global__ void gemm_naive(const float* __restrict__ x,
                           const float* __restrict__ Wlv, const float* __restrict__ blv,
                           const float* __restrict__ Wmu, const float* __restrict__ bmu,
                           float* __restrict__ out) {
  __shared__ float xr[512];
  int b = blockIdx.x;
  for (int i = threadIdx.x; i < 512; i += 256) xr[i] = x[(size_t)b * 512 + i];
  __syncthreads();
  int c = threadIdx.x;
  const float* w = (c < 128) ? (Wlv + c * 512) : (Wmu + (c - 128) * 512);
  float s = 0.f;
  for (int k = 0; k < 512; ++k) s += xr[k] * w[k];
  s += (c < 128) ? blv[c] : bmu[c - 128];
  float* o = (c < 128) ? (out + (size_t)b * 128 + c)
                       : (out + ((size_t)NB << 7) + (size_t)b * 128 + (c - 128));
  *o = s;
}

__global__ void embed_direct(const int* __restrict__ y, const float* __restrict__ We,
                             const float* __restrict__ be, float* __restrict__ out3) {
  size_t t = (size_t)blockIdx.x * 256 + threadIdx.x;
  int b = (int)(t >> 7), l = (int)(t & 127);
  out3[t] = We[(size_t)l * ED + y[b]] + be[l];
}

extern "C" void kernel_launch(void* const* d_in, const int* in_sizes, int n_in,
                              void* d_out, int out_size, void* d_ws, size_t ws_size,
                              hipStream_t stream) {
  const float* x   = (const float*)d_in[0];
  const int*   y   = (const int*)d_in[1];
  const float* Wlv = (const float*)d_in[2];
  const float* blv = (const float*)d_in[3];
  const float* Wmu = (const float*)d_in[4];
  const float* bmu = (const float*)d_in[5];
  const float* We  = (const float*)d_in[6];
  const float* be  = (const float*)d_in[7];
  float* out  = (float*)d_out;
  float* out3 = out + ((size_t)NB << 8);

  const size_t needW = 256 * 512 * sizeof(unsigned short);          // 256 KB
  const size_t needE = needW + (size_t)ED * 128 * sizeof(float);    // + 5.12 MB
  unsigned short* wbf = (unsigned short*)d_ws;
  float* embT = (float*)((char*)d_ws + needW);

  if (ws_size >= needE) {
    prep_all<<<512 + 313, 256, 0, stream>>>(Wlv, Wmu, wbf, We, be, embT);
    gemm_heads<<<NB / 32, 512, 0, stream>>>(x, wbf, blv, bmu, y, embT, out, 1);
  } else if (ws_size >= needW) {
    prep_all<<<512, 256, 0, stream>>>(Wlv, Wmu, wbf, We, be, (float*)d_ws);
    gemm_heads<<<NB / 32, 512, 0, stream>>>(x, wbf, blv, bmu, y, nullptr, out, 0);
    embed_direct<<<NB * 128 / 256, 256, 0, stream>>>(y, We, be, out3);
  } else {
    gemm_naive<<<NB, 256, 0, stream>>>(x, Wlv, blv, Wmu, bmu, out);
    embed_direct<<<NB * 128 / 256, 256, 0, stream>>>(y, We, be, out3);
  }
}